// Round 1
// baseline (8044.170 us; speedup 1.0000x reference)
//
#include <hip/hip_runtime.h>
#include <hip/hip_bf16.h>

#define Bv 32
#define Tv 512
#define Iv 512
#define Hv 1024
#define NG 4096  // 4*H

typedef short bf16x8 __attribute__((ext_vector_type(8)));   // 8 bf16 held as i16 (guide §3)
typedef float floatx16 __attribute__((ext_vector_type(16)));
typedef unsigned short u16;

__device__ __forceinline__ u16 f2bf(float f) {
  __hip_bfloat16 h = __float2bfloat16(f);
  return *reinterpret_cast<u16*>(&h);
}

__device__ __forceinline__ floatx16 mfma32(bf16x8 a, bf16x8 b, floatx16 c) {
  return __builtin_amdgcn_mfma_f32_32x32x16_bf16(a, b, c, 0, 0, 0);
}

// ---------------- init: zero barrier counter region (4KB) + hA double buffer (128KB)
__global__ void k_init(unsigned int* p, int n) {
  int i = blockIdx.x * blockDim.x + threadIdx.x;
  if (i < n) p[i] = 0u;
}

// ---------------- elementwise fp32 -> bf16
__global__ void k_f2bf(const float* __restrict__ in, u16* __restrict__ out, int n) {
  int i = blockIdx.x * blockDim.x + threadIdx.x;
  if (i < n) out[i] = f2bf(in[i]);
}

// ---------------- gather Wh into B-fragment layout: WhF[bl(64)][nt(2)][kt(64)][lane(64)][8]
// block bl owns units u0=16*bl..+15; local row r = gate*16+du, tiles: nt = r>>5, n_in_tile = r&31
__global__ void k_whf(const float* __restrict__ Wh, u16* __restrict__ whf) {
  int tid = blockIdx.x * 256 + threadIdx.x;   // 2048*256 = 524288
  int lane = tid & 63;
  int kt   = (tid >> 6) & 63;
  int nt   = (tid >> 12) & 1;
  int bl   = tid >> 13;
  int r    = nt * 32 + (lane & 31);
  int gate = r >> 4, du = r & 15;
  int row  = gate * Hv + bl * 16 + du;
  int k0   = kt * 16 + (lane >> 5) * 8;
  const float* s = Wh + (size_t)row * Hv + k0;
  u16* d = whf + (size_t)tid * 8;
#pragma unroll
  for (int j = 0; j < 8; ++j) d[j] = f2bf(s[j]);
}

// ---------------- xg GEMM: xg[tl][b][n] = sum_k x[b, t0+tl, k]*Wx[n,k] + bx[n] + bh[n]
// chunk rows m = b*Tc + tl, M = 32*Tc.  BM=BN=128, BK=32, 256 thr, wave -> 64x64 (2x2 of 32x32)
__global__ __launch_bounds__(256) void k_xg(const u16* __restrict__ xb, const u16* __restrict__ wxb,
                                            const float* __restrict__ bx, const float* __restrict__ bh,
                                            float* __restrict__ xg, int t0, int tcshift) {
  __shared__ u16 Al[128 * 40];
  __shared__ u16 Bl[128 * 40];
  int tid = threadIdx.x;
  int wave = tid >> 6, lane = tid & 63;
  int wm = wave & 1, wn = wave >> 1;
  int bm = blockIdx.x, bn = blockIdx.y;
  int Tc = 1 << tcshift;

  floatx16 acc[2][2];
#pragma unroll
  for (int a = 0; a < 2; ++a)
#pragma unroll
    for (int c = 0; c < 2; ++c)
#pragma unroll
      for (int r = 0; r < 16; ++r) acc[a][c][r] = 0.f;

  int lr = tid >> 1;            // 0..127
  int lk = (tid & 1) * 16;      // u16 offset 0 / 16
  int m  = bm * 128 + lr;
  int b  = m >> tcshift;
  int tl = m & (Tc - 1);
  const u16* asrc = xb + (size_t)(b * Tv + t0 + tl) * Iv + lk;
  int nrow = bn * 128 + lr;
  const u16* bsrc = wxb + (size_t)nrow * Iv + lk;
  u16* adst = &Al[lr * 40 + lk];
  u16* bdst = &Bl[lr * 40 + lk];

  for (int k0 = 0; k0 < Iv; k0 += 32) {
    __syncthreads();
    *(uint4*)adst       = *(const uint4*)(asrc);
    *(uint4*)(adst + 8) = *(const uint4*)(asrc + 8);
    *(uint4*)bdst       = *(const uint4*)(bsrc);
    *(uint4*)(bdst + 8) = *(const uint4*)(bsrc + 8);
    asrc += 32; bsrc += 32;
    __syncthreads();
#pragma unroll
    for (int kt = 0; kt < 2; ++kt) {
      int ko = kt * 16 + (lane >> 5) * 8;
      bf16x8 a0 = *(const bf16x8*)(&Al[(wm * 64 +      (lane & 31)) * 40 + ko]);
      bf16x8 a1 = *(const bf16x8*)(&Al[(wm * 64 + 32 + (lane & 31)) * 40 + ko]);
      bf16x8 b0 = *(const bf16x8*)(&Bl[(wn * 64 +      (lane & 31)) * 40 + ko]);
      bf16x8 b1 = *(const bf16x8*)(&Bl[(wn * 64 + 32 + (lane & 31)) * 40 + ko]);
      acc[0][0] = mfma32(a0, b0, acc[0][0]);
      acc[0][1] = mfma32(a0, b1, acc[0][1]);
      acc[1][0] = mfma32(a1, b0, acc[1][0]);
      acc[1][1] = mfma32(a1, b1, acc[1][1]);
    }
  }
  // epilogue: C/D 32x32 layout: col = lane&31, row = (reg&3)+8*(reg>>2)+4*(lane>>5)
#pragma unroll
  for (int mt = 0; mt < 2; ++mt) {
#pragma unroll
    for (int ntt = 0; ntt < 2; ++ntt) {
      int nGl = bn * 128 + wn * 64 + ntt * 32 + (lane & 31);
      float bias = bx[nGl] + bh[nGl];
#pragma unroll
      for (int r = 0; r < 16; ++r) {
        int mrow = (r & 3) + 8 * (r >> 2) + 4 * (lane >> 5);
        int mG = bm * 128 + wm * 64 + mt * 32 + mrow;
        int bb = mG >> tcshift;
        int tt = mG & (Tc - 1);
        xg[((size_t)(tt * Bv + bb) << 12) + nGl] = acc[mt][ntt][r] + bias;
      }
    }
  }
}

// ---------------- persistent scan: 64 blocks x 256 thr, one barrier per step
__global__ __launch_bounds__(256) void k_scan(const u16* __restrict__ whf, const float* __restrict__ xg,
                                              u16* __restrict__ hA, float* __restrict__ cbuf,
                                              float* __restrict__ out, int* cnt, int t0, int Tc) {
  __shared__ float gatesL[64 * 33];
  __shared__ float redL[2 * 32 * 33];
  int tid = threadIdx.x;
  int bl = blockIdx.x;                  // 0..63, owns units u0..u0+15
  int wave = tid >> 6, lane = tid & 63;
  int nt = wave & 1, kh = wave >> 1;    // wave -> (N-tile, k-half)
  int eu = tid & 15, eb = tid >> 4;     // epilogue: unit-in-block, batch 0..15 (+16)
  int u0 = bl * 16;

  float c0, c1;
  if (t0 == 0) { c0 = 0.f; c1 = 0.f; }
  else {
    c0 = cbuf[eb * Hv + u0 + eu];
    c1 = cbuf[(eb + 16) * Hv + u0 + eu];
  }
  const u16* wbase = whf + ((size_t)(bl * 2 + nt) << 15);  // 64*64*8 u16 per (bl,nt)
  int ktbase = kh * 32;

  for (int tl = 0; tl < Tc; ++tl) {
    int t = t0 + tl;
    // prefetch xg for this step's epilogue
    float xgv[4][2];
#pragma unroll
    for (int g = 0; g < 4; ++g)
#pragma unroll
      for (int b2 = 0; b2 < 2; ++b2) {
        int b = eb + 16 * b2;
        xgv[g][b2] = xg[((size_t)(tl * Bv + b) << 12) + g * Hv + u0 + eu];
      }

    const u16* hAr = hA + ((size_t)(t & 1) << 15);  // read buffer (32768 u16 each)
    floatx16 accA, accB;
#pragma unroll
    for (int r = 0; r < 16; ++r) { accA[r] = 0.f; accB[r] = 0.f; }
#pragma unroll
    for (int kk = 0; kk < 16; ++kk) {
      int kt = ktbase + kk;
      bf16x8 a = *(const bf16x8*)(hAr   + (size_t)((kt << 6) + lane) * 8);
      bf16x8 w = *(const bf16x8*)(wbase + (size_t)((kt << 6) + lane) * 8);
      accA = mfma32(a, w, accA);
    }
#pragma unroll
    for (int kk = 16; kk < 32; ++kk) {
      int kt = ktbase + kk;
      bf16x8 a = *(const bf16x8*)(hAr   + (size_t)((kt << 6) + lane) * 8);
      bf16x8 w = *(const bf16x8*)(wbase + (size_t)((kt << 6) + lane) * 8);
      accB = mfma32(a, w, accB);
    }
#pragma unroll
    for (int r = 0; r < 16; ++r) accA[r] += accB[r];

    int n = lane & 31;
    if (kh == 1) {
#pragma unroll
      for (int r = 0; r < 16; ++r) {
        int b = (r & 3) + 8 * (r >> 2) + 4 * (lane >> 5);
        redL[(nt * 32 + n) * 33 + b] = accA[r];
      }
    }
    __syncthreads();
    if (kh == 0) {
#pragma unroll
      for (int r = 0; r < 16; ++r) {
        int b = (r & 3) + 8 * (r >> 2) + 4 * (lane >> 5);
        gatesL[(nt * 32 + n) * 33 + b] = accA[r] + redL[(nt * 32 + n) * 33 + b];
      }
    }
    __syncthreads();

    // epilogue: thread -> (eu, eb) and (eu, eb+16)
    u16* hAw = hA + ((size_t)((t + 1) & 1) << 15);
#pragma unroll
    for (int b2 = 0; b2 < 2; ++b2) {
      int b = eb + 16 * b2;
      float gi = gatesL[(0 * 16 + eu) * 33 + b] + xgv[0][b2];
      float gf = gatesL[(1 * 16 + eu) * 33 + b] + xgv[1][b2];
      float gg = gatesL[(2 * 16 + eu) * 33 + b] + xgv[2][b2];
      float go = gatesL[(3 * 16 + eu) * 33 + b] + xgv[3][b2];
      float iv = 1.f / (1.f + __expf(-gi));
      float fv = 1.f / (1.f + __expf(-gf));
      float gv = 1.f - 2.f / (__expf(2.f * gg) + 1.f);
      float ov = 1.f / (1.f + __expf(-go));
      float& c = b2 ? c1 : c0;
      c = fv * c + iv * gv;
      float hval = ov * (1.f - 2.f / (__expf(2.f * c) + 1.f));
      out[((size_t)(b * Tv + t) << 10) + u0 + eu] = hval;
      // write into next step's A-fragment slot: lane = b + 32*(eu>>3), j = eu&7, kt = bl
      hAw[(((size_t)(bl << 6) + b + ((eu >> 3) << 5)) << 3) + (eu & 7)] = f2bf(hval);
    }

    // global barrier: monotonic counter, target 64*(t+1)
    __threadfence();
    __syncthreads();
    if (tid == 0) {
      __hip_atomic_fetch_add(cnt, 1, __ATOMIC_RELEASE, __HIP_MEMORY_SCOPE_AGENT);
      int target = 64 * (t + 1);
      while (__hip_atomic_load(cnt, __ATOMIC_ACQUIRE, __HIP_MEMORY_SCOPE_AGENT) < target)
        __builtin_amdgcn_s_sleep(1);
    }
    __syncthreads();
    __threadfence();
  }
  cbuf[eb * Hv + u0 + eu] = c0;
  cbuf[(eb + 16) * Hv + u0 + eu] = c1;
}

extern "C" void kernel_launch(void* const* d_in, const int* in_sizes, int n_in,
                              void* d_out, int out_size, void* d_ws, size_t ws_size,
                              hipStream_t stream) {
  const float* x  = (const float*)d_in[0];
  const float* Wx = (const float*)d_in[1];
  const float* bx = (const float*)d_in[2];
  const float* Wh = (const float*)d_in[3];
  const float* bh = (const float*)d_in[4];
  float* out = (float*)d_out;
  char* ws = (char*)d_ws;

  // ws layout
  int*   cnt = (int*)ws;                                   // [0, 4KB)
  u16*   hA  = (u16*)(ws + 4096);                          // 128 KB (2 x 64KB)
  float* cb  = (float*)(ws + 4096 + (128 << 10));          // 128 KB
  u16*   xb  = (u16*)(ws + 4096 + (256 << 10));            // 16 MB
  u16*   wxb = xb + (size_t)Bv * Tv * Iv;                  // 4 MB
  u16*   whf = wxb + (size_t)NG * Iv;                      // 8 MB
  float* xg  = (float*)(whf + (size_t)64 * 2 * 64 * 64 * 8);

  size_t fixedB = 4096 + (256ull << 10) +
                  ((size_t)Bv * Tv * Iv + (size_t)NG * Iv + (size_t)64 * 2 * 64 * 64 * 8) * 2;
  int tcshift = 9;
  while (tcshift > 2 && fixedB + (((size_t)Bv * NG * 4) << tcshift) > ws_size) --tcshift;
  int Tc = 1 << tcshift;

  k_init<<<132, 256, 0, stream>>>((unsigned int*)ws, (4096 + (128 << 10)) / 4);
  k_f2bf<<<(Bv * Tv * Iv) / 256, 256, 0, stream>>>(x, xb, Bv * Tv * Iv);
  k_f2bf<<<(NG * Iv) / 256, 256, 0, stream>>>(Wx, wxb, NG * Iv);
  k_whf<<<2048, 256, 0, stream>>>(Wh, whf);

  for (int t0 = 0; t0 < Tv; t0 += Tc) {
    k_xg<<<dim3(Tc / 4, 32), 256, 0, stream>>>(xb, wxb, bx, bh, xg, t0, tcshift);
    k_scan<<<64, 256, 0, stream>>>(whf, xg, hA, cb, out, cnt, t0, Tc);
  }
}

// Round 2
// 4443.867 us; speedup vs baseline: 1.8102x; 1.8102x over previous
//
#include <hip/hip_runtime.h>
#include <hip/hip_bf16.h>

#define Bv 32
#define Tv 512
#define Iv 512
#define Hv 1024
#define NG 4096  // 4*H

typedef short bf16x8 __attribute__((ext_vector_type(8)));   // 8 bf16 held as i16 (guide §3)
typedef float floatx16 __attribute__((ext_vector_type(16)));
typedef unsigned short u16;
typedef unsigned long long u64;

__device__ __forceinline__ u16 f2bf(float f) {
  __hip_bfloat16 h = __float2bfloat16(f);
  return *reinterpret_cast<u16*>(&h);
}

__device__ __forceinline__ floatx16 mfma32(bf16x8 a, bf16x8 b, floatx16 c) {
  return __builtin_amdgcn_mfma_f32_32x32x16_bf16(a, b, c, 0, 0, 0);
}

// relaxed agent-scope accesses: lower to global_load/store with sc1 (LLC-direct,
// bypass non-coherent per-XCD L2). No cache-maintenance instructions emitted.
__device__ __forceinline__ u64 ld_agent_u64(const u64* p) {
  return __hip_atomic_load(p, __ATOMIC_RELAXED, __HIP_MEMORY_SCOPE_AGENT);
}
__device__ __forceinline__ void st_agent_u64(u64* p, u64 v) {
  __hip_atomic_store(p, v, __ATOMIC_RELAXED, __HIP_MEMORY_SCOPE_AGENT);
}

__device__ __forceinline__ bf16x8 mk_frag(u64 lo, u64 hi) {
  union { u64 q[2]; bf16x8 v; } u;
  u.q[0] = lo; u.q[1] = hi;
  return u.v;
}

// ---------------- init: zero barrier counter region (4KB) + hA double buffer (128KB)
__global__ void k_init(unsigned int* p, int n) {
  int i = blockIdx.x * blockDim.x + threadIdx.x;
  if (i < n) p[i] = 0u;
}

// ---------------- elementwise fp32 -> bf16
__global__ void k_f2bf(const float* __restrict__ in, u16* __restrict__ out, int n) {
  int i = blockIdx.x * blockDim.x + threadIdx.x;
  if (i < n) out[i] = f2bf(in[i]);
}

// ---------------- gather Wh into B-fragment layout: WhF[bl(64)][nt(2)][kt(64)][lane(64)][8]
__global__ void k_whf(const float* __restrict__ Wh, u16* __restrict__ whf) {
  int tid = blockIdx.x * 256 + threadIdx.x;   // 2048*256 = 524288
  int lane = tid & 63;
  int kt   = (tid >> 6) & 63;
  int nt   = (tid >> 12) & 1;
  int bl   = tid >> 13;
  int r    = nt * 32 + (lane & 31);
  int gate = r >> 4, du = r & 15;
  int row  = gate * Hv + bl * 16 + du;
  int k0   = kt * 16 + (lane >> 5) * 8;
  const float* s = Wh + (size_t)row * Hv + k0;
  u16* d = whf + (size_t)tid * 8;
#pragma unroll
  for (int j = 0; j < 8; ++j) d[j] = f2bf(s[j]);
}

// ---------------- xg GEMM (unchanged from R1)
__global__ __launch_bounds__(256) void k_xg(const u16* __restrict__ xb, const u16* __restrict__ wxb,
                                            const float* __restrict__ bx, const float* __restrict__ bh,
                                            float* __restrict__ xg, int t0, int tcshift) {
  __shared__ u16 Al[128 * 40];
  __shared__ u16 Bl[128 * 40];
  int tid = threadIdx.x;
  int wave = tid >> 6, lane = tid & 63;
  int wm = wave & 1, wn = wave >> 1;
  int bm = blockIdx.x, bn = blockIdx.y;
  int Tc = 1 << tcshift;

  floatx16 acc[2][2];
#pragma unroll
  for (int a = 0; a < 2; ++a)
#pragma unroll
    for (int c = 0; c < 2; ++c)
#pragma unroll
      for (int r = 0; r < 16; ++r) acc[a][c][r] = 0.f;

  int lr = tid >> 1;
  int lk = (tid & 1) * 16;
  int m  = bm * 128 + lr;
  int b  = m >> tcshift;
  int tl = m & (Tc - 1);
  const u16* asrc = xb + (size_t)(b * Tv + t0 + tl) * Iv + lk;
  int nrow = bn * 128 + lr;
  const u16* bsrc = wxb + (size_t)nrow * Iv + lk;
  u16* adst = &Al[lr * 40 + lk];
  u16* bdst = &Bl[lr * 40 + lk];

  for (int k0 = 0; k0 < Iv; k0 += 32) {
    __syncthreads();
    *(uint4*)adst       = *(const uint4*)(asrc);
    *(uint4*)(adst + 8) = *(const uint4*)(asrc + 8);
    *(uint4*)bdst       = *(const uint4*)(bsrc);
    *(uint4*)(bdst + 8) = *(const uint4*)(bsrc + 8);
    asrc += 32; bsrc += 32;
    __syncthreads();
#pragma unroll
    for (int kt = 0; kt < 2; ++kt) {
      int ko = kt * 16 + (lane >> 5) * 8;
      bf16x8 a0 = *(const bf16x8*)(&Al[(wm * 64 +      (lane & 31)) * 40 + ko]);
      bf16x8 a1 = *(const bf16x8*)(&Al[(wm * 64 + 32 + (lane & 31)) * 40 + ko]);
      bf16x8 b0 = *(const bf16x8*)(&Bl[(wn * 64 +      (lane & 31)) * 40 + ko]);
      bf16x8 b1 = *(const bf16x8*)(&Bl[(wn * 64 + 32 + (lane & 31)) * 40 + ko]);
      acc[0][0] = mfma32(a0, b0, acc[0][0]);
      acc[0][1] = mfma32(a0, b1, acc[0][1]);
      acc[1][0] = mfma32(a1, b0, acc[1][0]);
      acc[1][1] = mfma32(a1, b1, acc[1][1]);
    }
  }
#pragma unroll
  for (int mt = 0; mt < 2; ++mt) {
#pragma unroll
    for (int ntt = 0; ntt < 2; ++ntt) {
      int nGl = bn * 128 + wn * 64 + ntt * 32 + (lane & 31);
      float bias = bx[nGl] + bh[nGl];
#pragma unroll
      for (int r = 0; r < 16; ++r) {
        int mrow = (r & 3) + 8 * (r >> 2) + 4 * (lane >> 5);
        int mG = bm * 128 + wm * 64 + mt * 32 + mrow;
        int bb = mG >> tcshift;
        int tt = mG & (Tc - 1);
        xg[((size_t)(tt * Bv + bb) << 12) + nGl] = acc[mt][ntt][r] + bias;
      }
    }
  }
}

// ---------------- persistent scan: 64 blocks x 256 thr, fence-free sc1 communication
__global__ __launch_bounds__(256) void k_scan(const u16* __restrict__ whf, const float* __restrict__ xg,
                                              u64* __restrict__ hA, float* __restrict__ cbuf,
                                              float* __restrict__ out, int* cnt, int t0, int Tc) {
  __shared__ float gatesL[64 * 33];
  __shared__ float redL[2 * 32 * 33];
  __shared__ u16 hstage[32 * 16];   // [batch][unit-in-block]
  int tid = threadIdx.x;
  int bl = blockIdx.x;                  // 0..63, owns units u0..u0+15
  int wave = tid >> 6, lane = tid & 63;
  int nt = wave & 1, kh = wave >> 1;    // wave -> (N-tile, k-half)
  int eu = tid & 15, eb = tid >> 4;     // epilogue: unit-in-block, batch 0..15 (+16)
  int u0 = bl * 16;

  float c0, c1;
  if (t0 == 0) { c0 = 0.f; c1 = 0.f; }
  else {
    c0 = cbuf[eb * Hv + u0 + eu];
    c1 = cbuf[(eb + 16) * Hv + u0 + eu];
  }
  const u16* wbase = whf + ((size_t)(bl * 2 + nt) << 15);  // 64*64*8 u16 per (bl,nt)
  int ktbase = kh * 32;

  for (int tl = 0; tl < Tc; ++tl) {
    int t = t0 + tl;
    // prefetch xg for this step's epilogue (plain cached loads, step-local)
    float xgv[4][2];
#pragma unroll
    for (int g = 0; g < 4; ++g)
#pragma unroll
      for (int b2 = 0; b2 < 2; ++b2) {
        int b = eb + 16 * b2;
        xgv[g][b2] = xg[((size_t)(tl * Bv + b) << 12) + g * Hv + u0 + eu];
      }

    const u64* hAr = hA + (size_t)(t & 1) * 8192;  // read buffer (8192 u64 each)
    floatx16 accA, accB;
#pragma unroll
    for (int r = 0; r < 16; ++r) { accA[r] = 0.f; accB[r] = 0.f; }
#pragma unroll
    for (int kk = 0; kk < 16; ++kk) {
      int kt = ktbase + kk;
      size_t fi = (size_t)((kt << 6) + lane) * 2;
      bf16x8 a = mk_frag(ld_agent_u64(hAr + fi), ld_agent_u64(hAr + fi + 1));
      bf16x8 w = *(const bf16x8*)(wbase + (size_t)((kt << 6) + lane) * 8);
      accA = mfma32(a, w, accA);
    }
#pragma unroll
    for (int kk = 16; kk < 32; ++kk) {
      int kt = ktbase + kk;
      size_t fi = (size_t)((kt << 6) + lane) * 2;
      bf16x8 a = mk_frag(ld_agent_u64(hAr + fi), ld_agent_u64(hAr + fi + 1));
      bf16x8 w = *(const bf16x8*)(wbase + (size_t)((kt << 6) + lane) * 8);
      accB = mfma32(a, w, accB);
    }
#pragma unroll
    for (int r = 0; r < 16; ++r) accA[r] += accB[r];

    int n = lane & 31;
    if (kh == 1) {
#pragma unroll
      for (int r = 0; r < 16; ++r) {
        int b = (r & 3) + 8 * (r >> 2) + 4 * (lane >> 5);
        redL[(nt * 32 + n) * 33 + b] = accA[r];
      }
    }
    __syncthreads();
    if (kh == 0) {
#pragma unroll
      for (int r = 0; r < 16; ++r) {
        int b = (r & 3) + 8 * (r >> 2) + 4 * (lane >> 5);
        gatesL[(nt * 32 + n) * 33 + b] = accA[r] + redL[(nt * 32 + n) * 33 + b];
      }
    }
    __syncthreads();

    // epilogue: thread -> (eu, eb) and (eu, eb+16); h -> LDS stage + fp32 out
#pragma unroll
    for (int b2 = 0; b2 < 2; ++b2) {
      int b = eb + 16 * b2;
      float gi = gatesL[(0 * 16 + eu) * 33 + b] + xgv[0][b2];
      float gf = gatesL[(1 * 16 + eu) * 33 + b] + xgv[1][b2];
      float gg = gatesL[(2 * 16 + eu) * 33 + b] + xgv[2][b2];
      float go = gatesL[(3 * 16 + eu) * 33 + b] + xgv[3][b2];
      float iv = 1.f / (1.f + __expf(-gi));
      float fv = 1.f / (1.f + __expf(-gf));
      float gv = 1.f - 2.f / (__expf(2.f * gg) + 1.f);
      float ov = 1.f / (1.f + __expf(-go));
      float& c = b2 ? c1 : c0;
      c = fv * c + iv * gv;
      float hval = ov * (1.f - 2.f / (__expf(2.f * c) + 1.f));
      out[((size_t)(b * Tv + t) << 10) + u0 + eu] = hval;
      hstage[b * 16 + eu] = f2bf(hval);
    }
    __syncthreads();

    // pack h into next step's A-fragment slots, u64 sc1 stores (LLC-direct)
    u64* hAw = hA + (size_t)((t + 1) & 1) * 8192;
    if (tid < 128) {
      int b = tid & 31, q = tid >> 5;       // q: 0..3
      int half = q >> 1, part = q & 1;      // unit half (0..7 / 8..15), u64 within 16B
      u64 v = *(const u64*)(&hstage[b * 16 + half * 8 + part * 4]);
      st_agent_u64(hAw + (size_t)((bl << 6) + b + (half << 5)) * 2 + part, v);
    }
    // drain this wave's global stores, then announce
    asm volatile("s_waitcnt vmcnt(0)" ::: "memory");
    __syncthreads();
    if (tid == 0) {
      __hip_atomic_fetch_add(cnt, 1, __ATOMIC_RELAXED, __HIP_MEMORY_SCOPE_AGENT);
      int target = 64 * (t + 1);
      while (__hip_atomic_load(cnt, __ATOMIC_RELAXED, __HIP_MEMORY_SCOPE_AGENT) < target)
        __builtin_amdgcn_s_sleep(1);
    }
    __syncthreads();   // also a compiler memory barrier: h loads stay after the spin
  }
  cbuf[eb * Hv + u0 + eu] = c0;
  cbuf[(eb + 16) * Hv + u0 + eu] = c1;
}

extern "C" void kernel_launch(void* const* d_in, const int* in_sizes, int n_in,
                              void* d_out, int out_size, void* d_ws, size_t ws_size,
                              hipStream_t stream) {
  const float* x  = (const float*)d_in[0];
  const float* Wx = (const float*)d_in[1];
  const float* bx = (const float*)d_in[2];
  const float* Wh = (const float*)d_in[3];
  const float* bh = (const float*)d_in[4];
  float* out = (float*)d_out;
  char* ws = (char*)d_ws;

  // ws layout
  int*   cnt = (int*)ws;                                   // [0, 4KB)
  u64*   hA  = (u64*)(ws + 4096);                          // 128 KB (2 x 64KB)
  float* cb  = (float*)(ws + 4096 + (128 << 10));          // 128 KB
  u16*   xb  = (u16*)(ws + 4096 + (256 << 10));            // 16 MB
  u16*   wxb = xb + (size_t)Bv * Tv * Iv;                  // 4 MB
  u16*   whf = wxb + (size_t)NG * Iv;                      // 8 MB
  float* xg  = (float*)(whf + (size_t)64 * 2 * 64 * 64 * 8);

  size_t fixedB = 4096 + (256ull << 10) +
                  ((size_t)Bv * Tv * Iv + (size_t)NG * Iv + (size_t)64 * 2 * 64 * 64 * 8) * 2;
  int tcshift = 9;
  while (tcshift > 2 && fixedB + (((size_t)Bv * NG * 4) << tcshift) > ws_size) --tcshift;
  int Tc = 1 << tcshift;

  k_init<<<132, 256, 0, stream>>>((unsigned int*)ws, (4096 + (128 << 10)) / 4);
  k_f2bf<<<(Bv * Tv * Iv) / 256, 256, 0, stream>>>(x, xb, Bv * Tv * Iv);
  k_f2bf<<<(NG * Iv) / 256, 256, 0, stream>>>(Wx, wxb, NG * Iv);
  k_whf<<<2048, 256, 0, stream>>>(Wh, whf);

  for (int t0 = 0; t0 < Tv; t0 += Tc) {
    k_xg<<<dim3(Tc / 4, 32), 256, 0, stream>>>(xb, wxb, bx, bh, xg, t0, tcshift);
    k_scan<<<64, 256, 0, stream>>>(whf, xg, hA, cb, out, cnt, t0, Tc);
  }
}

// Round 3
// 2674.815 us; speedup vs baseline: 3.0074x; 1.6614x over previous
//
#include <hip/hip_runtime.h>
#include <hip/hip_bf16.h>

#define Bv 32
#define Tv 512
#define Iv 512
#define Hv 1024
#define NG 4096  // 4*H

typedef short bf16x8 __attribute__((ext_vector_type(8)));   // 8 bf16 held as i16 (guide §3)
typedef float floatx16 __attribute__((ext_vector_type(16)));
typedef unsigned short u16;
typedef unsigned long long u64;

__device__ __forceinline__ u16 f2bf(float f) {
  __hip_bfloat16 h = __float2bfloat16(f);
  return *reinterpret_cast<u16*>(&h);
}

__device__ __forceinline__ floatx16 mfma32(bf16x8 a, bf16x8 b, floatx16 c) {
  return __builtin_amdgcn_mfma_f32_32x32x16_bf16(a, b, c, 0, 0, 0);
}

// relaxed agent-scope accesses: lower to global_load/store with sc1 (LLC-direct,
// bypass non-coherent per-XCD L2). No cache-maintenance instructions emitted.
__device__ __forceinline__ u64 ld_agent_u64(const u64* p) {
  return __hip_atomic_load(p, __ATOMIC_RELAXED, __HIP_MEMORY_SCOPE_AGENT);
}
__device__ __forceinline__ void st_agent_u16(u16* p, u16 v) {
  __hip_atomic_store(p, v, __ATOMIC_RELAXED, __HIP_MEMORY_SCOPE_AGENT);
}

__device__ __forceinline__ bf16x8 mk_frag(u64 lo, u64 hi) {
  union { u64 q[2]; bf16x8 v; } u;
  u.q[0] = lo; u.q[1] = hi;
  return u.v;
}

// ---------------- init: zero barrier counter region (4KB) + hA double buffer (128KB)
__global__ void k_init(unsigned int* p, int n) {
  int i = blockIdx.x * blockDim.x + threadIdx.x;
  if (i < n) p[i] = 0u;
}

// ---------------- elementwise fp32 -> bf16
__global__ void k_f2bf(const float* __restrict__ in, u16* __restrict__ out, int n) {
  int i = blockIdx.x * blockDim.x + threadIdx.x;
  if (i < n) out[i] = f2bf(in[i]);
}

// ---------------- gather Wh into B-fragment layout: WhF[bl(64)][nt(2)][kt(64)][lane(64)][8]
__global__ void k_whf(const float* __restrict__ Wh, u16* __restrict__ whf) {
  int tid = blockIdx.x * 256 + threadIdx.x;   // 2048*256 = 524288
  int lane = tid & 63;
  int kt   = (tid >> 6) & 63;
  int nt   = (tid >> 12) & 1;
  int bl   = tid >> 13;
  int r    = nt * 32 + (lane & 31);
  int gate = r >> 4, du = r & 15;
  int row  = gate * Hv + bl * 16 + du;
  int k0   = kt * 16 + (lane >> 5) * 8;
  const float* s = Wh + (size_t)row * Hv + k0;
  u16* d = whf + (size_t)tid * 8;
#pragma unroll
  for (int j = 0; j < 8; ++j) d[j] = f2bf(s[j]);
}

// ---------------- xg GEMM (unchanged)
__global__ __launch_bounds__(256) void k_xg(const u16* __restrict__ xb, const u16* __restrict__ wxb,
                                            const float* __restrict__ bx, const float* __restrict__ bh,
                                            float* __restrict__ xg, int t0, int tcshift) {
  __shared__ u16 Al[128 * 40];
  __shared__ u16 Bl[128 * 40];
  int tid = threadIdx.x;
  int wave = tid >> 6, lane = tid & 63;
  int wm = wave & 1, wn = wave >> 1;
  int bm = blockIdx.x, bn = blockIdx.y;
  int Tc = 1 << tcshift;

  floatx16 acc[2][2];
#pragma unroll
  for (int a = 0; a < 2; ++a)
#pragma unroll
    for (int c = 0; c < 2; ++c)
#pragma unroll
      for (int r = 0; r < 16; ++r) acc[a][c][r] = 0.f;

  int lr = tid >> 1;
  int lk = (tid & 1) * 16;
  int m  = bm * 128 + lr;
  int b  = m >> tcshift;
  int tl = m & (Tc - 1);
  const u16* asrc = xb + (size_t)(b * Tv + t0 + tl) * Iv + lk;
  int nrow = bn * 128 + lr;
  const u16* bsrc = wxb + (size_t)nrow * Iv + lk;
  u16* adst = &Al[lr * 40 + lk];
  u16* bdst = &Bl[lr * 40 + lk];

  for (int k0 = 0; k0 < Iv; k0 += 32) {
    __syncthreads();
    *(uint4*)adst       = *(const uint4*)(asrc);
    *(uint4*)(adst + 8) = *(const uint4*)(asrc + 8);
    *(uint4*)bdst       = *(const uint4*)(bsrc);
    *(uint4*)(bdst + 8) = *(const uint4*)(bsrc + 8);
    asrc += 32; bsrc += 32;
    __syncthreads();
#pragma unroll
    for (int kt = 0; kt < 2; ++kt) {
      int ko = kt * 16 + (lane >> 5) * 8;
      bf16x8 a0 = *(const bf16x8*)(&Al[(wm * 64 +      (lane & 31)) * 40 + ko]);
      bf16x8 a1 = *(const bf16x8*)(&Al[(wm * 64 + 32 + (lane & 31)) * 40 + ko]);
      bf16x8 b0 = *(const bf16x8*)(&Bl[(wn * 64 +      (lane & 31)) * 40 + ko]);
      bf16x8 b1 = *(const bf16x8*)(&Bl[(wn * 64 + 32 + (lane & 31)) * 40 + ko]);
      acc[0][0] = mfma32(a0, b0, acc[0][0]);
      acc[0][1] = mfma32(a0, b1, acc[0][1]);
      acc[1][0] = mfma32(a1, b0, acc[1][0]);
      acc[1][1] = mfma32(a1, b1, acc[1][1]);
    }
  }
#pragma unroll
  for (int mt = 0; mt < 2; ++mt) {
#pragma unroll
    for (int ntt = 0; ntt < 2; ++ntt) {
      int nGl = bn * 128 + wn * 64 + ntt * 32 + (lane & 31);
      float bias = bx[nGl] + bh[nGl];
#pragma unroll
      for (int r = 0; r < 16; ++r) {
        int mrow = (r & 3) + 8 * (r >> 2) + 4 * (lane >> 5);
        int mG = bm * 128 + wm * 64 + mt * 32 + mrow;
        int bb = mG >> tcshift;
        int tt = mG & (Tc - 1);
        xg[((size_t)(tt * Bv + bb) << 12) + nGl] = acc[mt][ntt][r] + bias;
      }
    }
  }
}

// ---------------- persistent scan: 64 blocks x 256 thr
// waves = k-split 4; weights pinned in VGPRs (128/lane); single LDS reduce pass
__global__ __launch_bounds__(256, 1) void k_scan(const u16* __restrict__ whf, const float* __restrict__ xg,
                                                 u64* __restrict__ hA, float* __restrict__ cbuf,
                                                 float* __restrict__ out, int* cnt, int t0, int Tc) {
  __shared__ float red[4][64][36];   // [kh][gate-row][batch] partials, 36864 B
  int tid = threadIdx.x;
  int bl = blockIdx.x;                  // 0..63, owns units u0..u0+15
  int kh = tid >> 6, lane = tid & 63;   // wave = k-quarter
  int eu = tid & 15, eb = tid >> 4;     // epilogue: unit-in-block, batch 0..15 (+16)
  int u0 = bl * 16;

  // preload weights into registers, once: w0/w1 = nt0/nt1 fragments for kt=kh*16+kk
  bf16x8 w0[16], w1[16];
  {
    const u16* wb0 = whf + ((size_t)(bl * 2 + 0) << 15);
    const u16* wb1 = whf + ((size_t)(bl * 2 + 1) << 15);
#pragma unroll
    for (int kk = 0; kk < 16; ++kk) {
      int kt = kh * 16 + kk;
      w0[kk] = *(const bf16x8*)(wb0 + (size_t)((kt << 6) + lane) * 8);
      w1[kk] = *(const bf16x8*)(wb1 + (size_t)((kt << 6) + lane) * 8);
    }
  }

  float c0, c1;
  if (t0 == 0) { c0 = 0.f; c1 = 0.f; }
  else {
    c0 = cbuf[eb * Hv + u0 + eu];
    c1 = cbuf[(eb + 16) * Hv + u0 + eu];
  }

  u16* hA16 = (u16*)hA;

  // xg prefetch for tl=0
  float xgv[4][2];
#pragma unroll
  for (int g = 0; g < 4; ++g)
#pragma unroll
    for (int b2 = 0; b2 < 2; ++b2)
      xgv[g][b2] = xg[((size_t)(0 * Bv + eb + 16 * b2) << 12) + g * Hv + u0 + eu];

  for (int tl = 0; tl < Tc; ++tl) {
    int t = t0 + tl;
    const u64* hAr = hA + (size_t)(t & 1) * 8192;  // read buffer (8192 u64 each)

    floatx16 acc0, acc1;
#pragma unroll
    for (int r = 0; r < 16; ++r) { acc0[r] = 0.f; acc1[r] = 0.f; }
#pragma unroll
    for (int kk = 0; kk < 16; ++kk) {
      int kt = kh * 16 + kk;
      size_t fi = (size_t)((kt << 6) + lane) * 2;
      bf16x8 a = mk_frag(ld_agent_u64(hAr + fi), ld_agent_u64(hAr + fi + 1));
      acc0 = mfma32(a, w0[kk], acc0);
      acc1 = mfma32(a, w1[kk], acc1);
    }

    // write k-partials: row = nt*32 + (lane&31); b = (r&3) + 8*(r>>2) + 4*(lane>>5)
    {
      int n = lane & 31;
      int bq = 4 * (lane >> 5);
#pragma unroll
      for (int rq = 0; rq < 4; ++rq) {
        float4 v0 = make_float4(acc0[rq * 4 + 0], acc0[rq * 4 + 1], acc0[rq * 4 + 2], acc0[rq * 4 + 3]);
        float4 v1 = make_float4(acc1[rq * 4 + 0], acc1[rq * 4 + 1], acc1[rq * 4 + 2], acc1[rq * 4 + 3]);
        *(float4*)&red[kh][n][8 * rq + bq]      = v0;
        *(float4*)&red[kh][32 + n][8 * rq + bq] = v1;
      }
    }

    // prefetch next step's xg while reduce/epilogue runs (off the post-barrier chain)
    float xgn[4][2];
    {
      int tln = (tl + 1 < Tc) ? tl + 1 : tl;
#pragma unroll
      for (int g = 0; g < 4; ++g)
#pragma unroll
        for (int b2 = 0; b2 < 2; ++b2)
          xgn[g][b2] = xg[((size_t)(tln * Bv + eb + 16 * b2) << 12) + g * Hv + u0 + eu];
    }

    __syncthreads();

    // epilogue: thread -> (eu, eb) and (eu, eb+16)
    u16* hAw16 = hA16 + (size_t)((t + 1) & 1) * 32768;
#pragma unroll
    for (int b2 = 0; b2 < 2; ++b2) {
      int b = eb + 16 * b2;
      float gsum[4];
#pragma unroll
      for (int g = 0; g < 4; ++g) {
        int r = g * 16 + eu;
        gsum[g] = red[0][r][b] + red[1][r][b] + red[2][r][b] + red[3][r][b] + xgv[g][b2];
      }
      float iv = 1.f / (1.f + __expf(-gsum[0]));
      float fv = 1.f / (1.f + __expf(-gsum[1]));
      float gv = 1.f - 2.f / (__expf(2.f * gsum[2]) + 1.f);
      float ov = 1.f / (1.f + __expf(-gsum[3]));
      float& c = b2 ? c1 : c0;
      c = fv * c + iv * gv;
      float hval = ov * (1.f - 2.f / (__expf(2.f * c) + 1.f));
      // h fragment slot: lane = b + 32*(eu>>3), j = eu&7, kt-slot = bl
      st_agent_u16(hAw16 + ((size_t)((bl << 6) + b + ((eu >> 3) << 5)) << 3) + (eu & 7), f2bf(hval));
      out[((size_t)(b * Tv + t) << 10) + u0 + eu] = hval;
    }

    // drain stores (and straggling xg prefetch), then arrive + spin
    asm volatile("s_waitcnt vmcnt(0)" ::: "memory");
    __syncthreads();
    if (tid == 0) {
      __hip_atomic_fetch_add(cnt, 1, __ATOMIC_RELAXED, __HIP_MEMORY_SCOPE_AGENT);
      int target = 64 * (t + 1);
      while (__hip_atomic_load(cnt, __ATOMIC_RELAXED, __HIP_MEMORY_SCOPE_AGENT) < target) { }
    }
    __syncthreads();   // compiler memory barrier: next step's h loads stay after the spin

#pragma unroll
    for (int g = 0; g < 4; ++g)
#pragma unroll
      for (int b2 = 0; b2 < 2; ++b2) xgv[g][b2] = xgn[g][b2];
  }
  cbuf[eb * Hv + u0 + eu] = c0;
  cbuf[(eb + 16) * Hv + u0 + eu] = c1;
}

extern "C" void kernel_launch(void* const* d_in, const int* in_sizes, int n_in,
                              void* d_out, int out_size, void* d_ws, size_t ws_size,
                              hipStream_t stream) {
  const float* x  = (const float*)d_in[0];
  const float* Wx = (const float*)d_in[1];
  const float* bx = (const float*)d_in[2];
  const float* Wh = (const float*)d_in[3];
  const float* bh = (const float*)d_in[4];
  float* out = (float*)d_out;
  char* ws = (char*)d_ws;

  // ws layout
  int*   cnt = (int*)ws;                                   // [0, 4KB)
  u64*   hA  = (u64*)(ws + 4096);                          // 128 KB (2 x 64KB)
  float* cb  = (float*)(ws + 4096 + (128 << 10));          // 128 KB
  u16*   xb  = (u16*)(ws + 4096 + (256 << 10));            // 16 MB
  u16*   wxb = xb + (size_t)Bv * Tv * Iv;                  // 4 MB
  u16*   whf = wxb + (size_t)NG * Iv;                      // 8 MB
  float* xg  = (float*)(whf + (size_t)64 * 2 * 64 * 64 * 8);

  size_t fixedB = 4096 + (256ull << 10) +
                  ((size_t)Bv * Tv * Iv + (size_t)NG * Iv + (size_t)64 * 2 * 64 * 64 * 8) * 2;
  int tcshift = 9;
  while (tcshift > 2 && fixedB + (((size_t)Bv * NG * 4) << tcshift) > ws_size) --tcshift;
  int Tc = 1 << tcshift;

  k_init<<<132, 256, 0, stream>>>((unsigned int*)ws, (4096 + (128 << 10)) / 4);
  k_f2bf<<<(Bv * Tv * Iv) / 256, 256, 0, stream>>>(x, xb, Bv * Tv * Iv);
  k_f2bf<<<(NG * Iv) / 256, 256, 0, stream>>>(Wx, wxb, NG * Iv);
  k_whf<<<2048, 256, 0, stream>>>(Wh, whf);

  for (int t0 = 0; t0 < Tv; t0 += Tc) {
    k_xg<<<dim3(Tc / 4, 32), 256, 0, stream>>>(xb, wxb, bx, bh, xg, t0, tcshift);
    k_scan<<<64, 256, 0, stream>>>(whf, xg, hA, cb, out, cnt, t0, Tc);
  }
}